// Round 1
// baseline (704.362 us; speedup 1.0000x reference)
//
#include <hip/hip_runtime.h>

// NetDensity: per-net bbox -> separable per-bin overlap -> weighted rank-1
// scatter onto 256x256 H/V congestion maps.
// Key identity: ox[n,:] = prefix_x(ex_n) with ex_n having <=4 nonzeros
// (corner stencil), same in y. So
//   H = prefix_x(prefix_y( sum_n ch_n * ex_n (x) ey_n ))
// => 16 atomic scatter points per net per map, then two 1-D inclusive scans.

#define NBX 256
#define NBY 256
#define SP 258          // scatter grid covers indices 0..257 (v==512 edge case)
#define SPITCH 258
#define SELEMS (SP * SPITCH)

#define XL_ 0.0f
#define BSX_ 2.0f
#define BSY_ 2.0f
#define INV_BSX 0.5f
#define INV_BSY 0.5f

__constant__ float c_risa[47] = {
    1.0f, 1.0f, 1.0f, 1.0f,
    1.0828f, 1.1536f, 1.2206f, 1.2823f, 1.3385f, 1.3991f, 1.4493f,
    1.6899f, 1.6899f, 1.6899f, 1.6899f, 1.6899f,
    1.8924f, 1.8924f, 1.8924f, 1.8924f, 1.8924f,
    2.0743f, 2.0743f, 2.0743f, 2.0743f, 2.0743f,
    2.2334f, 2.2334f, 2.2334f, 2.2334f, 2.2334f,
    2.3892f, 2.3892f, 2.3892f, 2.3892f, 2.3892f,
    2.5356f, 2.5356f, 2.5356f, 2.5356f, 2.5356f,
    2.6625f, 2.6625f, 2.6625f, 2.6625f, 2.6625f,
    2.7933f};

// Build the 4-entry first-difference stencil of the overlap function for
// interval [vmin, vmax] against bins of width BS starting at XL.
__device__ __forceinline__ void stencil(float vmin, float vmax, float inv_bs,
                                        float bs, int* idx, float* w) {
    float t1 = (vmin - XL_) * inv_bs;
    int k1 = (int)floorf(t1);
    k1 = min(max(k1, 0), NBX);
    float f1 = t1 - (float)k1;
    float t2 = (vmax - XL_) * inv_bs;
    int k2 = (int)floorf(t2);
    k2 = min(max(k2, 0), NBX);
    float f2 = t2 - (float)k2;
    idx[0] = k1;     w[0] =  bs * (1.0f - f1);
    idx[1] = k1 + 1; w[1] =  bs * f1;
    idx[2] = k2;     w[2] = -bs * (1.0f - f2);
    idx[3] = k2 + 1; w[3] = -bs * f2;
}

__global__ void net_scatter(const float* __restrict__ pin_pos,
                            const int* __restrict__ netpin_start,
                            const int* __restrict__ flat_netpin,
                            const float* __restrict__ net_weights,
                            float* __restrict__ SH, float* __restrict__ SV,
                            int num_nets) {
    int n = blockIdx.x * blockDim.x + threadIdx.x;
    if (n >= num_nets) return;
    int s = netpin_start[n];
    int e = netpin_start[n + 1];
    int cnt = e - s;
    if (cnt <= 0) return;

    float xmin = 1e30f, xmax = -1e30f, ymin = 1e30f, ymax = -1e30f;
    for (int i = s; i < e; ++i) {
        int p = flat_netpin[i];
        float2 xy = *reinterpret_cast<const float2*>(pin_pos + 2 * (long)p);
        xmin = fminf(xmin, xy.x);
        xmax = fmaxf(xmax, xy.x);
        ymin = fminf(ymin, xy.y);
        ymax = fmaxf(ymax, xy.y);
    }

    float wt = c_risa[min(cnt, 46)] * net_weights[n];
    float dx = xmax - xmin;
    float dy = ymax - ymin;
    float ch = (dy > 0.0f) ? wt / fmaxf(dy, 1e-12f) : 0.0f;
    float cv = (dx > 0.0f) ? wt / fmaxf(dx, 1e-12f) : 0.0f;
    if (ch == 0.0f && cv == 0.0f) return;

    int xi[4]; float xw[4];
    int yi[4]; float yw[4];
    stencil(xmin, xmax, INV_BSX, BSX_, xi, xw);
    stencil(ymin, ymax, INV_BSY, BSY_, yi, yw);

#pragma unroll
    for (int a = 0; a < 4; ++a) {
        int rowoff = xi[a] * SPITCH;
        float wx = xw[a];
#pragma unroll
        for (int b = 0; b < 4; ++b) {
            float wxy = wx * yw[b];
            int off = rowoff + yi[b];
            atomicAdd(&SH[off], ch * wxy);
            atomicAdd(&SV[off], cv * wxy);
        }
    }
}

// Inclusive scan along x (rows of S) for each column y, both maps in one block.
__global__ void scan_x(float* __restrict__ SH, float* __restrict__ SV) {
    __shared__ float sh[256];
    __shared__ float sv[256];
    int y = blockIdx.x;       // column 0..255
    int t = threadIdx.x;      // x index 0..255
    sh[t] = SH[t * SPITCH + y];
    sv[t] = SV[t * SPITCH + y];
    __syncthreads();
    for (int off = 1; off < 256; off <<= 1) {
        float ah = (t >= off) ? sh[t - off] : 0.0f;
        float av = (t >= off) ? sv[t - off] : 0.0f;
        __syncthreads();
        sh[t] += ah;
        sv[t] += av;
        __syncthreads();
    }
    SH[t * SPITCH + y] = sh[t];
    SV[t * SPITCH + y] = sv[t];
}

// Inclusive scan along y for each row x; writes all three outputs coalesced.
__global__ void scan_y_out(const float* __restrict__ SH,
                           const float* __restrict__ SV,
                           float* __restrict__ out) {
    __shared__ float sh[256];
    __shared__ float sv[256];
    int x = blockIdx.x;       // row 0..255
    int t = threadIdx.x;      // y index 0..255
    sh[t] = SH[x * SPITCH + t];
    sv[t] = SV[x * SPITCH + t];
    __syncthreads();
    for (int off = 1; off < 256; off <<= 1) {
        float ah = (t >= off) ? sh[t - off] : 0.0f;
        float av = (t >= off) ? sv[t - off] : 0.0f;
        __syncthreads();
        sh[t] += ah;
        sv[t] += av;
        __syncthreads();
    }
    float h = sh[t];
    float v = sv[t];
    int idx = x * NBY + t;
    out[idx] = fabsf(h) + fabsf(v);
    out[NBX * NBY + idx] = h;
    out[2 * NBX * NBY + idx] = v;
}

extern "C" void kernel_launch(void* const* d_in, const int* in_sizes, int n_in,
                              void* d_out, int out_size, void* d_ws, size_t ws_size,
                              hipStream_t stream) {
    const float* pin_pos = (const float*)d_in[0];
    const int* netpin_start = (const int*)d_in[1];
    const int* flat_netpin = (const int*)d_in[2];
    const float* net_weights = (const float*)d_in[3];
    int num_nets = in_sizes[1] - 1;

    float* SH = (float*)d_ws;
    float* SV = SH + SELEMS;

    // Accumulators must start at zero every launch (harness does not re-poison).
    hipMemsetAsync(d_ws, 0, 2 * SELEMS * sizeof(float), stream);

    int nb = (num_nets + 255) / 256;
    net_scatter<<<nb, 256, 0, stream>>>(pin_pos, netpin_start, flat_netpin,
                                        net_weights, SH, SV, num_nets);
    scan_x<<<NBY, 256, 0, stream>>>(SH, SV);
    scan_y_out<<<NBX, 256, 0, stream>>>(SH, SV, (float*)d_out);
}

// Round 2
// 445.566 us; speedup vs baseline: 1.5808x; 1.5808x over previous
//
#include <hip/hip_runtime.h>

// NetDensity via corner-stencil scatter + 2D prefix sums.
//   H = prefix_x(prefix_y( sum_n ch_n * ex_n (x) ey_n ))
// Each net contributes <=16 points per map. R1 showed device-scope fp32
// atomics execute memory-side (WRITE_SIZE 258MB for a 512KB accumulator,
// 12 G atomics/s). R2: per-XCD replica accumulators + workgroup-scope
// hardware fadd so the RMW stays in the local XCD's L2.

#define NBX 256
#define NBY 256
#define GP 256                      // scatter grid pitch (points >=256 dropped)
#define CELLS (NBX * NBY)
#define NREP 8                      // one replica per XCD
#define REP_STRIDE (CELLS * 2)      // floats per replica, interleaved {H,V}

#define BS_ 2.0f
#define INV_BS 0.5f

__constant__ float c_risa[47] = {
    1.0f, 1.0f, 1.0f, 1.0f,
    1.0828f, 1.1536f, 1.2206f, 1.2823f, 1.3385f, 1.3991f, 1.4493f,
    1.6899f, 1.6899f, 1.6899f, 1.6899f, 1.6899f,
    1.8924f, 1.8924f, 1.8924f, 1.8924f, 1.8924f,
    2.0743f, 2.0743f, 2.0743f, 2.0743f, 2.0743f,
    2.2334f, 2.2334f, 2.2334f, 2.2334f, 2.2334f,
    2.3892f, 2.3892f, 2.3892f, 2.3892f, 2.3892f,
    2.5356f, 2.5356f, 2.5356f, 2.5356f, 2.5356f,
    2.6625f, 2.6625f, 2.6625f, 2.6625f, 2.6625f,
    2.7933f};

__device__ __forceinline__ unsigned xcc_id() {
    unsigned x;
    asm volatile("s_getreg_b32 %0, hwreg(HW_REG_XCC_ID)" : "=s"(x));
    return x & (NREP - 1);
}

// 4-entry first-difference stencil of the bin-overlap function for [vmin,vmax].
__device__ __forceinline__ void stencil(float vmin, float vmax, int* idx, float* w) {
    float t1 = vmin * INV_BS;
    int k1 = (int)floorf(t1);
    k1 = min(max(k1, 0), NBX);
    float f1 = t1 - (float)k1;
    float t2 = vmax * INV_BS;
    int k2 = (int)floorf(t2);
    k2 = min(max(k2, 0), NBX);
    float f2 = t2 - (float)k2;
    idx[0] = k1;     w[0] =  BS_ * (1.0f - f1);
    idx[1] = k1 + 1; w[1] =  BS_ * f1;
    idx[2] = k2;     w[2] = -BS_ * (1.0f - f2);
    idx[3] = k2 + 1; w[3] = -BS_ * f2;
}

__global__ void net_scatter(const float* __restrict__ pin_pos,
                            const int* __restrict__ netpin_start,
                            const int* __restrict__ flat_netpin,
                            const float* __restrict__ net_weights,
                            float* __restrict__ S, int num_nets, int dev_scope) {
    int n = blockIdx.x * blockDim.x + threadIdx.x;
    if (n >= num_nets) return;
    int s = netpin_start[n];
    int e = netpin_start[n + 1];
    int cnt = e - s;
    if (cnt <= 0) return;

    float xmin = 1e30f, xmax = -1e30f, ymin = 1e30f, ymax = -1e30f;
    for (int i = s; i < e; ++i) {
        int p = flat_netpin[i];
        float2 xy = *reinterpret_cast<const float2*>(pin_pos + 2 * (long)p);
        xmin = fminf(xmin, xy.x);
        xmax = fmaxf(xmax, xy.x);
        ymin = fminf(ymin, xy.y);
        ymax = fmaxf(ymax, xy.y);
    }

    float wt = c_risa[min(cnt, 46)] * net_weights[n];
    float dx = xmax - xmin;
    float dy = ymax - ymin;
    float ch = (dy > 0.0f) ? wt / fmaxf(dy, 1e-12f) : 0.0f;
    float cv = (dx > 0.0f) ? wt / fmaxf(dx, 1e-12f) : 0.0f;
    if (ch == 0.0f && cv == 0.0f) return;

    float* rep = S;
    if (!dev_scope) rep += (size_t)xcc_id() * REP_STRIDE;

    int xi[4]; float xw[4];
    int yi[4]; float yw[4];
    stencil(xmin, xmax, xi, xw);
    stencil(ymin, ymax, yi, yw);

#pragma unroll
    for (int a = 0; a < 4; ++a) {
        if (xi[a] >= NBX) continue;   // can only influence output rows >=256
        int rowoff = xi[a] * GP;
        float wx = xw[a];
#pragma unroll
        for (int b = 0; b < 4; ++b) {
            if (yi[b] >= NBY) continue;
            float wxy = wx * yw[b];
            int off = (rowoff + yi[b]) * 2;
            if (dev_scope) {
                atomicAdd(&rep[off], ch * wxy);
                atomicAdd(&rep[off + 1], cv * wxy);
            } else {
                // Stays in the issuing XCD's L2 (replica is XCD-private).
                __hip_atomic_fetch_add(&rep[off], ch * wxy,
                                       __ATOMIC_RELAXED, __HIP_MEMORY_SCOPE_WORKGROUP);
                __hip_atomic_fetch_add(&rep[off + 1], cv * wxy,
                                       __ATOMIC_RELAXED, __HIP_MEMORY_SCOPE_WORKGROUP);
            }
        }
    }
}

// Sum replicas + inclusive scan along x for each column y.
__global__ void scan_x(const float* __restrict__ S, float* __restrict__ T, int nrep) {
    __shared__ float sh[256];
    __shared__ float sv[256];
    int y = blockIdx.x;
    int t = threadIdx.x;          // x index
    int cell = (t * GP + y) * 2;
    float h = 0.0f, v = 0.0f;
    for (int r = 0; r < nrep; ++r) {
        h += S[(size_t)r * REP_STRIDE + cell];
        v += S[(size_t)r * REP_STRIDE + cell + 1];
    }
    sh[t] = h; sv[t] = v;
    __syncthreads();
    for (int off = 1; off < 256; off <<= 1) {
        float ah = (t >= off) ? sh[t - off] : 0.0f;
        float av = (t >= off) ? sv[t - off] : 0.0f;
        __syncthreads();
        sh[t] += ah;
        sv[t] += av;
        __syncthreads();
    }
    T[cell] = sh[t];
    T[cell + 1] = sv[t];
}

// Inclusive scan along y for each row x; writes the three outputs.
__global__ void scan_y_out(const float* __restrict__ T, float* __restrict__ out) {
    __shared__ float sh[256];
    __shared__ float sv[256];
    int x = blockIdx.x;
    int t = threadIdx.x;          // y index
    int cell = (x * GP + t) * 2;
    sh[t] = T[cell];
    sv[t] = T[cell + 1];
    __syncthreads();
    for (int off = 1; off < 256; off <<= 1) {
        float ah = (t >= off) ? sh[t - off] : 0.0f;
        float av = (t >= off) ? sv[t - off] : 0.0f;
        __syncthreads();
        sh[t] += ah;
        sv[t] += av;
        __syncthreads();
    }
    float h = sh[t];
    float v = sv[t];
    int idx = x * NBY + t;
    out[idx] = fabsf(h) + fabsf(v);
    out[NBX * NBY + idx] = h;
    out[2 * NBX * NBY + idx] = v;
}

extern "C" void kernel_launch(void* const* d_in, const int* in_sizes, int n_in,
                              void* d_out, int out_size, void* d_ws, size_t ws_size,
                              hipStream_t stream) {
    const float* pin_pos = (const float*)d_in[0];
    const int* netpin_start = (const int*)d_in[1];
    const int* flat_netpin = (const int*)d_in[2];
    const float* net_weights = (const float*)d_in[3];
    int num_nets = in_sizes[1] - 1;

    size_t need_fast = (size_t)(NREP + 1) * REP_STRIDE * sizeof(float);
    int nrep, dev_scope;
    float* S = (float*)d_ws;
    float* T;
    if (ws_size >= need_fast) {
        nrep = NREP; dev_scope = 0;
        T = S + (size_t)NREP * REP_STRIDE;
    } else {
        nrep = 1; dev_scope = 1;
        T = S + REP_STRIDE;
    }

    // Replica accumulators must start at zero on every launch.
    hipMemsetAsync(S, 0, (size_t)nrep * REP_STRIDE * sizeof(float), stream);

    int nb = (num_nets + 255) / 256;
    net_scatter<<<nb, 256, 0, stream>>>(pin_pos, netpin_start, flat_netpin,
                                        net_weights, S, num_nets, dev_scope);
    scan_x<<<NBY, 256, 0, stream>>>(S, T, nrep);
    scan_y_out<<<NBX, 256, 0, stream>>>(T, (float*)d_out);
}

// Round 3
// 103.812 us; speedup vs baseline: 6.7850x; 4.2921x over previous
//
#include <hip/hip_runtime.h>

// NetDensity via corner-stencil scatter + 2D prefix sums.
//   H = prefix_x(prefix_y( sum_n ch_n * ex_n (x) ey_n ))   (<=16 pts/net/map)
// R1/R2 evidence: global fp32 atomics execute memory-side (WRITE_SIZE 258MB
// for a 512KB accumulator, ~19G atomics/s ceiling) regardless of scope.
// R3: no global atomics. Per-net records -> LDS-privatized 32-row strip
// accumulators (64KB, fits exactly) -> dense partial merge -> scans.

#define NBX 256
#define NBY 256
#define CELLS (NBX * NBY)
#define STRIPS 8
#define SROWS 32                 // rows per strip (32*256*2*4B = 64KB LDS)
#define STRIP_FLOATS (SROWS * NBY * 2)
#define MAXB 64                  // max blocks per strip

#define BS_ 2.0f
#define INV_BS 0.5f

__constant__ float c_risa[47] = {
    1.0f, 1.0f, 1.0f, 1.0f,
    1.0828f, 1.1536f, 1.2206f, 1.2823f, 1.3385f, 1.3991f, 1.4493f,
    1.6899f, 1.6899f, 1.6899f, 1.6899f, 1.6899f,
    1.8924f, 1.8924f, 1.8924f, 1.8924f, 1.8924f,
    2.0743f, 2.0743f, 2.0743f, 2.0743f, 2.0743f,
    2.2334f, 2.2334f, 2.2334f, 2.2334f, 2.2334f,
    2.3892f, 2.3892f, 2.3892f, 2.3892f, 2.3892f,
    2.5356f, 2.5356f, 2.5356f, 2.5356f, 2.5356f,
    2.6625f, 2.6625f, 2.6625f, 2.6625f, 2.6625f,
    2.7933f};

// 4-entry first-difference stencil of the bin-overlap function for [vmin,vmax].
__device__ __forceinline__ void stencil(float vmin, float vmax, int* idx, float* w) {
    float t1 = vmin * INV_BS;
    int k1 = (int)floorf(t1);
    k1 = min(max(k1, 0), 256);
    float f1 = t1 - (float)k1;
    float t2 = vmax * INV_BS;
    int k2 = (int)floorf(t2);
    k2 = min(max(k2, 0), 256);
    float f2 = t2 - (float)k2;
    idx[0] = k1;     w[0] =  BS_ * (1.0f - f1);
    idx[1] = k1 + 1; w[1] =  BS_ * f1;
    idx[2] = k2;     w[2] = -BS_ * (1.0f - f2);
    idx[3] = k2 + 1; w[3] = -BS_ * f2;
}

// Pass 1: per-net bbox + demand coefficients (the only random-gather pass).
__global__ void bbox_pass(const float* __restrict__ pin_pos,
                          const int* __restrict__ netpin_start,
                          const int* __restrict__ flat_netpin,
                          const float* __restrict__ net_weights,
                          float4* __restrict__ recA, float2* __restrict__ recB,
                          int num_nets) {
    int n = blockIdx.x * blockDim.x + threadIdx.x;
    if (n >= num_nets) return;
    int s = netpin_start[n];
    int e = netpin_start[n + 1];
    int cnt = e - s;
    float xmin = 1e30f, xmax = -1e30f, ymin = 1e30f, ymax = -1e30f;
    for (int i = s; i < e; ++i) {
        int p = flat_netpin[i];
        float2 xy = *reinterpret_cast<const float2*>(pin_pos + 2 * (long)p);
        xmin = fminf(xmin, xy.x);
        xmax = fmaxf(xmax, xy.x);
        ymin = fminf(ymin, xy.y);
        ymax = fmaxf(ymax, xy.y);
    }
    float ch = 0.0f, cv = 0.0f;
    if (cnt > 0) {
        float wt = c_risa[min(cnt, 46)] * net_weights[n];
        float dx = xmax - xmin;
        float dy = ymax - ymin;
        ch = (dy > 0.0f) ? wt / fmaxf(dy, 1e-12f) : 0.0f;
        cv = (dx > 0.0f) ? wt / fmaxf(dx, 1e-12f) : 0.0f;
    } else {
        xmin = xmax = ymin = ymax = 0.0f;
    }
    recA[n] = make_float4(xmin, xmax, ymin, ymax);
    recB[n] = make_float2(ch, cv);
}

// Pass 2: LDS-privatized strip accumulation. Block = (strip, net-chunk).
__global__ __launch_bounds__(256) void strip_scatter(
        const float4* __restrict__ recA, const float2* __restrict__ recB,
        float* __restrict__ P, int num_nets, int B) {
    __shared__ float lds[STRIP_FLOATS];   // exactly 64KB
    int strip = blockIdx.x / B;
    int blk = blockIdx.x - strip * B;
    int lo = strip * SROWS;
    int tid = threadIdx.x;
    for (int j = tid; j < STRIP_FLOATS; j += 256) lds[j] = 0.0f;
    __syncthreads();

    int chunk = (num_nets + B - 1) / B;
    int i0 = blk * chunk;
    int i1 = min(i0 + chunk, num_nets);
    for (int i = i0 + tid; i < i1; i += 256) {
        float2 cc = recB[i];
        float ch = cc.x, cv = cc.y;
        if (ch == 0.0f && cv == 0.0f) continue;
        float4 bb = recA[i];
        int xi[4]; float xw[4];
        stencil(bb.x, bb.y, xi, xw);
        int rr[4];
        bool any = false;
#pragma unroll
        for (int a = 0; a < 4; ++a) {
            rr[a] = xi[a] - lo;
            any = any || ((unsigned)rr[a] < SROWS);   // implies xi < 256 too
        }
        if (!any) continue;
        int yi[4]; float yw[4];
        stencil(bb.z, bb.w, yi, yw);
#pragma unroll
        for (int a = 0; a < 4; ++a) {
            if ((unsigned)rr[a] >= SROWS) continue;
            float wxh = ch * xw[a];
            float wxv = cv * xw[a];
            int rbase = rr[a] * NBY;
#pragma unroll
            for (int b = 0; b < 4; ++b) {
                if (yi[b] >= NBY) continue;
                int off = (rbase + yi[b]) * 2;
                atomicAdd(&lds[off],     wxh * yw[b]);
                atomicAdd(&lds[off + 1], wxv * yw[b]);
            }
        }
    }
    __syncthreads();
    // Dense coalesced flush of the whole strip tile.
    float2* dst = reinterpret_cast<float2*>(P + (size_t)blockIdx.x * STRIP_FLOATS);
    const float2* src = reinterpret_cast<const float2*>(lds);
    for (int j = tid; j < STRIP_FLOATS / 2; j += 256) dst[j] = src[j];
}

// Fallback (tiny ws): fused bbox + device-scope atomic scatter into dense grid.
__global__ void fused_atomic(const float* __restrict__ pin_pos,
                             const int* __restrict__ netpin_start,
                             const int* __restrict__ flat_netpin,
                             const float* __restrict__ net_weights,
                             float* __restrict__ S, int num_nets) {
    int n = blockIdx.x * blockDim.x + threadIdx.x;
    if (n >= num_nets) return;
    int s = netpin_start[n];
    int e = netpin_start[n + 1];
    int cnt = e - s;
    if (cnt <= 0) return;
    float xmin = 1e30f, xmax = -1e30f, ymin = 1e30f, ymax = -1e30f;
    for (int i = s; i < e; ++i) {
        int p = flat_netpin[i];
        float2 xy = *reinterpret_cast<const float2*>(pin_pos + 2 * (long)p);
        xmin = fminf(xmin, xy.x);
        xmax = fmaxf(xmax, xy.x);
        ymin = fminf(ymin, xy.y);
        ymax = fmaxf(ymax, xy.y);
    }
    float wt = c_risa[min(cnt, 46)] * net_weights[n];
    float dx = xmax - xmin;
    float dy = ymax - ymin;
    float ch = (dy > 0.0f) ? wt / fmaxf(dy, 1e-12f) : 0.0f;
    float cv = (dx > 0.0f) ? wt / fmaxf(dx, 1e-12f) : 0.0f;
    if (ch == 0.0f && cv == 0.0f) return;
    int xi[4]; float xw[4];
    int yi[4]; float yw[4];
    stencil(xmin, xmax, xi, xw);
    stencil(ymin, ymax, yi, yw);
#pragma unroll
    for (int a = 0; a < 4; ++a) {
        if (xi[a] >= NBX) continue;
        int rbase = xi[a] * NBY;
        float wxh = ch * xw[a];
        float wxv = cv * xw[a];
#pragma unroll
        for (int b = 0; b < 4; ++b) {
            if (yi[b] >= NBY) continue;
            int off = (rbase + yi[b]) * 2;
            atomicAdd(&S[off], wxh * yw[b]);
            atomicAdd(&S[off + 1], wxv * yw[b]);
        }
    }
}

// Pass 3: merge the B partials per strip and inclusive-scan along y.
// Block = output row x; thread = column y. P layout: [strip][b][row][col][2].
__global__ void merge_scany(const float* __restrict__ P, float2* __restrict__ T,
                            int B) {
    __shared__ float sh[256];
    __shared__ float sv[256];
    int x = blockIdx.x;
    int t = threadIdx.x;
    int strip = x >> 5;          // SROWS = 32
    int r = x & 31;
    size_t rowoff = (size_t)(r * NBY + t) * 2;
    const float* base = P + (size_t)strip * B * STRIP_FLOATS;
    float h = 0.0f, v = 0.0f;
    for (int b = 0; b < B; ++b) {
        const float* p = base + (size_t)b * STRIP_FLOATS + rowoff;
        h += p[0];
        v += p[1];
    }
    sh[t] = h; sv[t] = v;
    __syncthreads();
    for (int off = 1; off < 256; off <<= 1) {
        float ah = (t >= off) ? sh[t - off] : 0.0f;
        float av = (t >= off) ? sv[t - off] : 0.0f;
        __syncthreads();
        sh[t] += ah;
        sv[t] += av;
        __syncthreads();
    }
    T[x * NBY + t] = make_float2(sh[t], sv[t]);
}

// Pass 4: inclusive scan along x per column y; write the three outputs.
__global__ void scanx_out(const float2* __restrict__ T, float* __restrict__ out) {
    __shared__ float sh[256];
    __shared__ float sv[256];
    int y = blockIdx.x;
    int t = threadIdx.x;          // t = x
    float2 c = T[t * NBY + y];
    sh[t] = c.x; sv[t] = c.y;
    __syncthreads();
    for (int off = 1; off < 256; off <<= 1) {
        float ah = (t >= off) ? sh[t - off] : 0.0f;
        float av = (t >= off) ? sv[t - off] : 0.0f;
        __syncthreads();
        sh[t] += ah;
        sv[t] += av;
        __syncthreads();
    }
    float h = sh[t], v = sv[t];
    int idx = t * NBY + y;
    out[idx] = fabsf(h) + fabsf(v);
    out[CELLS + idx] = h;
    out[2 * CELLS + idx] = v;
}

extern "C" void kernel_launch(void* const* d_in, const int* in_sizes, int n_in,
                              void* d_out, int out_size, void* d_ws, size_t ws_size,
                              hipStream_t stream) {
    const float* pin_pos = (const float*)d_in[0];
    const int* netpin_start = (const int*)d_in[1];
    const int* flat_netpin = (const int*)d_in[2];
    const float* net_weights = (const float*)d_in[3];
    int num_nets = in_sizes[1] - 1;

    size_t rec_bytes = (size_t)num_nets * 24;              // float4 + float2
    size_t t_bytes = (size_t)CELLS * sizeof(float2);       // 512KB
    size_t strip_bytes = (size_t)STRIP_FLOATS * sizeof(float);  // 64KB

    // Pick the largest B (blocks per strip) whose partial buffer fits ws.
    int B = 0;
    for (int cand = MAXB; cand >= 1; cand >>= 1) {
        size_t need = rec_bytes + (size_t)STRIPS * cand * strip_bytes + t_bytes;
        if (need <= ws_size) { B = cand; break; }
    }

    float* out = (float*)d_out;
    int nb = (num_nets + 255) / 256;

    if (B >= 1) {
        // Fast path: no global atomics anywhere.
        float4* recA = (float4*)d_ws;
        float2* recB = (float2*)((char*)d_ws + (size_t)num_nets * 16);
        float* P = (float*)((char*)d_ws + rec_bytes);
        float2* T = (float2*)((char*)d_ws + rec_bytes +
                              (size_t)STRIPS * B * strip_bytes);
        bbox_pass<<<nb, 256, 0, stream>>>(pin_pos, netpin_start, flat_netpin,
                                          net_weights, recA, recB, num_nets);
        strip_scatter<<<STRIPS * B, 256, 0, stream>>>(recA, recB, P, num_nets, B);
        merge_scany<<<NBX, 256, 0, stream>>>(P, T, B);
        scanx_out<<<NBY, 256, 0, stream>>>(T, out);
    } else {
        // Tiny-ws fallback: device atomics into dense grid (same layout as B=1).
        float* S = (float*)d_ws;                       // CELLS*2 floats
        float2* T = (float2*)((char*)d_ws + (size_t)CELLS * 2 * sizeof(float));
        hipMemsetAsync(S, 0, (size_t)CELLS * 2 * sizeof(float), stream);
        fused_atomic<<<nb, 256, 0, stream>>>(pin_pos, netpin_start, flat_netpin,
                                             net_weights, S, num_nets);
        merge_scany<<<NBX, 256, 0, stream>>>(S, T, 1);
        scanx_out<<<NBY, 256, 0, stream>>>(T, out);
    }
}